// Round 4
// baseline (476.818 us; speedup 1.0000x reference)
//
#include <hip/hip_runtime.h>
#include <hip/hip_bf16.h>

// SVXSoftmax: cos = norm(input) @ norm(weight)^T ; margin transform ; *32
// B=512, D=512, C=100000.  out[512][100000] f32.
//
// r4: packed bf16-normalized A in L2 (fragment-order, 1KB coalesced loads).
// GEMM block = 64 classes: phase0 single-pass stages RAW bf16 W rows into
// swizzled LDS (invnorm applied POST-MFMA in epilogue), one barrier, then
// K-loop with distance-4 A prefetch (5-buf rotation). Plain stores (NT was
// +43% write amplification). 2 blocks/CU.

#define S_SCALE 32.0f
#define MARGIN  0.35f
#define T_BOOST 0.2f
#define EPSN    1e-12f

constexpr int Bn = 512;      // batch
constexpr int Dn = 512;      // dim
constexpr int Cn = 100000;   // classes
constexpr int BN = 64;       // classes per block

typedef __attribute__((ext_vector_type(8))) short bf16x8;
typedef __attribute__((ext_vector_type(4))) float f32x4;

static __device__ inline unsigned short f32_bf16(float f) {
    unsigned int u = __float_as_uint(f);
    u += 0x7FFFu + ((u >> 16) & 1u);     // round-to-nearest-even
    return (unsigned short)(u >> 16);
}

// packed A layout: byte = (g<<14) + (s<<10) + (lane<<4) + j*2
//   g = row>>4, s = col>>5, lane = ((col>>3)&3)*16 + (row&15), j = col&7
__global__ __launch_bounds__(256) void prep_kernel(const float* __restrict__ in,
                                                   const float* __restrict__ w,
                                                   const int* __restrict__ label,
                                                   float* __restrict__ gt,
                                                   unsigned short* __restrict__ in_p) {
    int b = blockIdx.x, t = threadIdx.x;
    const float* irow = in + (size_t)b * Dn;
    int lab = label[b];
    const float* wrow = w + (size_t)lab * Dn;
    int c = 2 * t;
    float xa = irow[c], xb = irow[c + 1];
    float ya = wrow[c], yb = wrow[c + 1];
    float s_ii = xa*xa + xb*xb, s_ww = ya*ya + yb*yb, s_iw = xa*ya + xb*yb;
    #pragma unroll
    for (int off = 32; off; off >>= 1) {
        s_ii += __shfl_xor(s_ii, off);
        s_ww += __shfl_xor(s_ww, off);
        s_iw += __shfl_xor(s_iw, off);
    }
    __shared__ float r0[4], r1[4], r2[4], bc[1];
    int wid = t >> 6;
    if ((t & 63) == 0) { r0[wid] = s_ii; r1[wid] = s_ww; r2[wid] = s_iw; }
    __syncthreads();
    if (t == 0) {
        float a  = r0[0] + r0[1] + r0[2] + r0[3];
        float cc = r1[0] + r1[1] + r1[2] + r1[3];
        float d  = r2[0] + r2[1] + r2[2] + r2[3];
        float inv_i = 1.0f / fmaxf(sqrtf(a), EPSN);
        float g = d * inv_i / fmaxf(sqrtf(cc), EPSN);
        gt[b] = fminf(fmaxf(g, -1.0f), 1.0f);
        bc[0] = inv_i;
    }
    __syncthreads();
    float inv_i = bc[0];
    int g = b >> 4, l15 = b & 15;
    int s = t >> 4, lk = (t >> 2) & 3, j2 = (t & 3) * 4;
    int lane = lk * 16 + l15;
    unsigned int off = (unsigned)((g << 14) + (s << 10) + (lane << 4)) + j2;
    unsigned int h0 = f32_bf16(xa * inv_i), h1 = f32_bf16(xb * inv_i);
    *(unsigned int*)((char*)in_p + off) = h0 | (h1 << 16);
}

// ---------------- fused convert+GEMM+margin ----------------
__global__ __launch_bounds__(512, 4) void gemm_kernel(const unsigned short* __restrict__ in_p,
                                                      const float* __restrict__ w,
                                                      const float* __restrict__ gt,
                                                      const int* __restrict__ label,
                                                      float* __restrict__ out) {
    __shared__ unsigned short Bs[BN * 512];   // 64 KB, raw bf16 W
    __shared__ float inv_s[BN];
    char* bsb = (char*)Bs;
    int t = threadIdx.x, wid = t >> 6, lane = t & 63;
    int cbase = blockIdx.x * BN;

    // ---- phase 0 (single pass): raw W -> bf16 -> swizzled LDS, sumsq on the fly ----
    {
        int rl = (wid << 3) | (lane >> 3);        // local row 0..63, 8 lanes/row
        int rg = cbase + rl; if (rg >= Cn) rg = Cn - 1;
        const float* wr = w + (size_t)rg * Dn;
        int kc = lane & 7;
        float ssum = 0.f;
        #pragma unroll
        for (int i = 0; i < 8; ++i) {
            f32x4 v0 = *(const f32x4*)(wr + kc * 8 + i * 64);
            f32x4 v1 = *(const f32x4*)(wr + kc * 8 + i * 64 + 4);
            ssum += v0[0]*v0[0] + v0[1]*v0[1] + v0[2]*v0[2] + v0[3]*v0[3]
                  + v1[0]*v1[0] + v1[1]*v1[1] + v1[2]*v1[2] + v1[3]*v1[3];
            bf16x8 hv;
            #pragma unroll
            for (int j = 0; j < 4; ++j) {
                hv[j]     = (short)f32_bf16(v0[j]);
                hv[4 + j] = (short)f32_bf16(v1[j]);
            }
            unsigned int off = (unsigned)(((rl << 10) + (kc << 4) + (i << 7)) ^ ((rl & 7) << 4));
            *(bf16x8*)(bsb + off) = hv;
        }
        ssum += __shfl_xor(ssum, 1); ssum += __shfl_xor(ssum, 2); ssum += __shfl_xor(ssum, 4);
        if (kc == 0) inv_s[rl] = 1.0f / fmaxf(sqrtf(ssum), EPSN);
    }
    __syncthreads();                              // the ONLY barrier

    int l15 = lane & 15, lk = lane >> 4;
    float invc[4];
    #pragma unroll
    for (int nf = 0; nf < 4; ++nf) invc[nf] = inv_s[nf * 16 + l15];

    // ---- two M-passes: wave = 32M x 64N, distance-4 A prefetch ----
    for (int p = 0; p < 2; ++p) {
        const char* ap = (const char*)in_p + ((size_t)((p * 16 + wid * 2) << 14)) + (lane << 4);

        f32x4 acc[2][4];
        #pragma unroll
        for (int m = 0; m < 2; ++m)
            #pragma unroll
            for (int n = 0; n < 4; ++n) acc[m][n] = (f32x4){0.f, 0.f, 0.f, 0.f};

        bf16x8 ar[5][2];
        #pragma unroll
        for (int s = 0; s < 4; ++s)
            #pragma unroll
            for (int m = 0; m < 2; ++m)
                ar[s][m] = *(const bf16x8*)(ap + (m << 14) + (s << 10));

        #pragma unroll
        for (int s = 0; s < 16; ++s) {
            if (s + 4 < 16) {
                #pragma unroll
                for (int m = 0; m < 2; ++m)
                    ar[(s + 4) % 5][m] = *(const bf16x8*)(ap + (m << 14) + ((s + 4) << 10));
            }
            bf16x8 bfrag[4];
            #pragma unroll
            for (int nf = 0; nf < 4; ++nf) {
                int br = nf * 16 + l15;
                bfrag[nf] = *(const bf16x8*)(bsb + ((((br << 10) + (s << 6) + (lk << 4))) ^ ((br & 7) << 4)));
            }
            #pragma unroll
            for (int m = 0; m < 2; ++m)
                #pragma unroll
                for (int nf = 0; nf < 4; ++nf)
                    acc[m][nf] = __builtin_amdgcn_mfma_f32_16x16x32_bf16(ar[s % 5][m], bfrag[nf], acc[m][nf], 0, 0, 0);
        }

        // ---- epilogue for this M-pass (stores overlap next pass's loads) ----
        #pragma unroll
        for (int m = 0; m < 2; ++m) {
            #pragma unroll
            for (int r = 0; r < 4; ++r) {
                int b_row = p * 256 + wid * 32 + m * 16 + lk * 4 + r;
                float thr = gt[b_row] - MARGIN;
                int lab   = label[b_row];
                float gv  = thr * S_SCALE;
                size_t obase = (size_t)b_row * Cn;
                #pragma unroll
                for (int nf = 0; nf < 4; ++nf) {
                    int c = cbase + nf * 16 + l15;
                    if (c < Cn) {
                        float cosv = acc[m][nf][r] * invc[nf];
                        cosv = fminf(fmaxf(cosv, -1.0f), 1.0f);
                        float o = (cosv > thr) ? ((T_BOOST + 1.0f) * cosv + T_BOOST) : cosv;
                        o *= S_SCALE;
                        if (c == lab) o = gv;
                        out[obase + c] = o;
                    }
                }
            }
        }
    }
}

extern "C" void kernel_launch(void* const* d_in, const int* in_sizes, int n_in,
                              void* d_out, int out_size, void* d_ws, size_t ws_size,
                              hipStream_t stream) {
    const float* in  = (const float*)d_in[0];
    const float* w   = (const float*)d_in[1];
    const int* label = (const int*)d_in[2];
    float* out = (float*)d_out;

    char* ws = (char*)d_ws;
    float* gt            = (float*)ws;                   // 512 f32
    unsigned short* in_p = (unsigned short*)(ws + 4096); // packed 512KB

    prep_kernel<<<dim3(Bn), dim3(256), 0, stream>>>(in, w, label, gt, in_p);
    gemm_kernel<<<dim3((Cn + BN - 1) / BN), dim3(512), 0, stream>>>(in_p, w, gt, label, out);
}